// Round 11
// baseline (226.272 us; speedup 1.0000x reference)
//
#include <hip/hip_runtime.h>
#include <hip/hip_bf16.h>

typedef float f32x4 __attribute__((ext_vector_type(4)));
typedef short bfx8 __attribute__((ext_vector_type(8)));   // 8 bf16 in 4 VGPRs

typedef const __attribute__((address_space(1))) void* gvp;
typedef __attribute__((address_space(3))) void* lvp;

static __device__ __forceinline__ unsigned short f2bf(float f) {
    return __builtin_bit_cast(unsigned short, __float2bfloat16(f));
}

static __device__ __forceinline__ bfx8 cvt8(f32x4 lo, f32x4 hi) {
    bfx8 r;
    r[0] = (short)f2bf(lo[0]); r[1] = (short)f2bf(lo[1]);
    r[2] = (short)f2bf(lo[2]); r[3] = (short)f2bf(lo[3]);
    r[4] = (short)f2bf(hi[0]); r[5] = (short)f2bf(hi[1]);
    r[6] = (short)f2bf(hi[2]); r[7] = (short)f2bf(hi[3]);
    return r;
}

// ---------------------------------------------------------------------------
// Kernel 0: cast + transpose weights into WcatT[768][768] bf16.
// ---------------------------------------------------------------------------
__global__ void prep_w(const float* __restrict__ Wk, const float* __restrict__ Wq,
                       const float* __restrict__ Wv, unsigned short* __restrict__ WT) {
    const int n = blockIdx.x;       // 0..767
    const int e = threadIdx.x;      // 0..767
    const int which = n >> 8;
    const int h = n & 255;
    const float* W = (which == 0) ? Wq : (which == 1) ? Wk : Wv;
    WT[(size_t)n * 768 + e] = f2bf(W[(size_t)e * 256 + h]);
}

// ---------------------------------------------------------------------------
// Kernel 0b: X f32 -> bf16, vectorized (memory-bound, ~50µs).
// ---------------------------------------------------------------------------
__global__ void cvt_x(const float* __restrict__ X, unsigned short* __restrict__ Xb,
                      long n) {
    long i = ((long)blockIdx.x * 256 + threadIdx.x) * 8;
    const long stride = (long)gridDim.x * 256 * 8;
    for (; i < n; i += stride) {
        f32x4 lo = *(const f32x4*)(X + i);
        f32x4 hi = *(const f32x4*)(X + i + 4);
        *(bfx8*)(Xb + i) = cvt8(lo, hi);
    }
}

// ---------------------------------------------------------------------------
// Kernel 1: QKV = Xb @ [Wq|Wk|Wv].  ROUND 11: 128x256 tile (one block = Q, K
// or V of one batch), 4 waves (2x2: wave = 64m x 128n), BK=32, 256 threads.
// acc[4][8] = 128 f32/lane (+frags ~48, addr ~25 -> ~200 VGPR, under the
// 256 budget; session rule: NEVER 512-thr blocks, they spill).
// 2-deep counted-vmcnt pipeline: 6 gload_lds/step, steady wait vmcnt(6).
// Staged traffic 885MB vs r10's 1.18GB (-25%); MFMA/staged-byte +33%.
// LDS (48KB): A0[0,8K) A1[8K,16K) B0[16K,32K) B1[32K,48K); 64B rows,
// swizzle byte ^= ((row>>1)&3)<<4 (2-way max) on BOTH src and read.
//   bn 0/1 (Q,K): out [t][h];  bn 2 (V): operand-swapped -> V'[h][t]
// ---------------------------------------------------------------------------
__global__ __launch_bounds__(256) void qkv_gemm(const unsigned short* __restrict__ Xb,
                                                const unsigned short* __restrict__ WT,
                                                unsigned short* __restrict__ QKV,
                                                int b0, int nwg) {
    __shared__ __align__(16) char LDS[49152];

    const int tid = threadIdx.x;
    const int bid = blockIdx.x;
    // bijective XCD remap (m204): Q,K,V blocks of one batch on one XCD
    const int q = nwg >> 3, r = nwg & 7;
    const int xcd = bid & 7, idx = bid >> 3;
    const int l = (xcd < r ? xcd * (q + 1) : r * (q + 1) + (xcd - r) * q) + idx;
    const int bn = l % 3;                          // 0=Q 1=K 2=V
    const int bm = l / 3;                          // batch within chunk
    const int m0 = bm * 128;
    const int n0 = bn * 256;
    const int w = tid >> 6, lane = tid & 63;
    const int wr = w >> 1, wc = w & 1;             // 2m x 2n waves
    const int lrow = lane & 15, lhi = lane >> 4;
    const bool vswap = (bn == 2);

    f32x4 acc[4][8];
    const f32x4 zero = {0.f, 0.f, 0.f, 0.f};
#pragma unroll
    for (int i = 0; i < 4; ++i)
#pragma unroll
        for (int j = 0; j < 8; ++j) acc[i][j] = zero;

    // stage one K-step: A 8KB (2 issues) + B 16KB (4 issues)
#define STAGE(kt, bs)                                                          \
    {                                                                          \
        const int k0s = (kt) * 32;                                             \
        _Pragma("unroll")                                                      \
        for (int i = 0; i < 2; ++i) {                                          \
            const int f = i * 256 + tid;                                       \
            const int row = f >> 2;                                            \
            const int cbs = ((f & 3) * 16) ^ (((row >> 1) & 3) << 4);          \
            const unsigned short* ga = Xb + (size_t)(m0 + row) * 768 + k0s + (cbs >> 1); \
            char* lpa = LDS + (bs) * 8192 + i * 4096 + tid * 16;               \
            __builtin_amdgcn_global_load_lds((gvp)ga, (lvp)lpa, 16, 0, 0);     \
        }                                                                      \
        _Pragma("unroll")                                                      \
        for (int i = 0; i < 4; ++i) {                                          \
            const int f = i * 256 + tid;                                       \
            const int row = f >> 2;                                            \
            const int cbs = ((f & 3) * 16) ^ (((row >> 1) & 3) << 4);          \
            const unsigned short* gb = WT + (size_t)(n0 + row) * 768 + k0s + (cbs >> 1); \
            char* lpb = LDS + 16384 + (bs) * 16384 + i * 4096 + tid * 16;      \
            __builtin_amdgcn_global_load_lds((gvp)gb, (lvp)lpb, 16, 0, 0);     \
        }                                                                      \
    }

    STAGE(0, 0);
    STAGE(1, 1);

    int cur = 0;
    for (int kt = 0; kt < 24; ++kt) {
        if (kt < 23) asm volatile("s_waitcnt vmcnt(6)" ::: "memory");
        else         asm volatile("s_waitcnt vmcnt(0)" ::: "memory");
        __builtin_amdgcn_s_barrier();     // tile kt resident for ALL waves
        {
            const int cb = lhi * 16;                       // 16B slot in 64B row
            bfx8 a[4], bb4[8];
#pragma unroll
            for (int mi = 0; mi < 4; ++mi) {
                const int arow = wr * 64 + mi * 16 + lrow;
                a[mi] = *(const bfx8*)(LDS + cur * 8192 + arow * 64 +
                                       (cb ^ (((arow >> 1) & 3) << 4)));
            }
#pragma unroll
            for (int ni = 0; ni < 8; ++ni) {
                const int brow = wc * 128 + ni * 16 + lrow;
                bb4[ni] = *(const bfx8*)(LDS + 16384 + cur * 16384 + brow * 64 +
                                         (cb ^ (((brow >> 1) & 3) << 4)));
            }
            if (!vswap) {
#pragma unroll
                for (int mi = 0; mi < 4; ++mi)
#pragma unroll
                    for (int ni = 0; ni < 8; ++ni)
                        acc[mi][ni] = __builtin_amdgcn_mfma_f32_16x16x32_bf16(
                            a[mi], bb4[ni], acc[mi][ni], 0, 0, 0);
            } else {
#pragma unroll
                for (int mi = 0; mi < 4; ++mi)
#pragma unroll
                    for (int ni = 0; ni < 8; ++ni)
                        acc[mi][ni] = __builtin_amdgcn_mfma_f32_16x16x32_bf16(
                            bb4[ni], a[mi], acc[mi][ni], 0, 0, 0);   // D[n][m]
            }
        }
        __builtin_amdgcn_s_barrier();     // all waves done reading buf[cur]
        if (kt < 22) STAGE(kt + 2, cur);  // refill retired buffer
        cur ^= 1;
    }

    // epilogue: direct fragment stores (r9-proven; write volume is legit)
    const int b = b0 + bm;
    const size_t base = ((size_t)(b * 3 + bn)) << 15;
    if (!vswap) {
#pragma unroll
        for (int mi = 0; mi < 4; ++mi)
#pragma unroll
            for (int ni = 0; ni < 8; ++ni) {
                const int t = wr * 64 + mi * 16 + lhi * 4;
                const int h = wc * 128 + ni * 16 + lrow;
#pragma unroll
                for (int j = 0; j < 4; ++j)
                    QKV[base + (size_t)(t + j) * 256 + h] = f2bf(acc[mi][ni][j]);
            }
    } else {
#pragma unroll
        for (int mi = 0; mi < 4; ++mi)
#pragma unroll
            for (int ni = 0; ni < 8; ++ni) {
                const int h = wc * 128 + ni * 16 + lhi * 4;   // D row = n = h
                const int t = wr * 64 + mi * 16 + lrow;       // D col = m = t
#pragma unroll
                for (int j = 0; j < 4; ++j)
                    QKV[base + (size_t)(h + j) * 128 + t] = f2bf(acc[mi][ni][j]);
            }
    }
}

// ---------------------------------------------------------------------------
// Kernel 2: per-batch causal attention (unchanged — passing).
// ---------------------------------------------------------------------------
__global__ __launch_bounds__(512) void attn(const unsigned short* __restrict__ QKV,
                                            float* __restrict__ Out) {
    __shared__ unsigned short Kl[128][264];
    __shared__ unsigned short Vt[256][136];

    const int b = blockIdx.x;
    const int tid = threadIdx.x;
    const int w = tid >> 6, lane = tid & 63;
    const int lrow = lane & 15, lhi = lane >> 4;

    const unsigned short* Qb = QKV + ((size_t)(b * 3 + 0) << 15);
    const unsigned short* Kb = QKV + ((size_t)(b * 3 + 1) << 15);
    const unsigned short* Vb = QKV + ((size_t)(b * 3 + 2) << 15);

    const int t0 = w * 16;
    bfx8 aq[8];
#pragma unroll
    for (int kk = 0; kk < 8; ++kk)
        aq[kk] = *(const bfx8*)(Qb + (size_t)(t0 + lrow) * 256 + kk * 32 + lhi * 8);

#pragma unroll
    for (int i = 0; i < 8; ++i) {
        int f = i * 512 + tid;
        {
            int row = f >> 5, c = (f & 31) * 8;
            *(bfx8*)&Kl[row][c] = *(const bfx8*)(Kb + (size_t)row * 256 + c);
        }
        {
            int row = f >> 4, c = (f & 15) * 8;
            *(bfx8*)&Vt[row][c] = *(const bfx8*)(Vb + (size_t)row * 128 + c);
        }
    }
    __syncthreads();

    f32x4 sacc[8];
    const f32x4 zero = {0.f, 0.f, 0.f, 0.f};
#pragma unroll
    for (int sj = 0; sj < 8; ++sj) sacc[sj] = zero;
#pragma unroll
    for (int kk = 0; kk < 8; ++kk) {
        const int kb = kk * 32 + lhi * 8;
#pragma unroll
        for (int sj = 0; sj < 8; ++sj) {
            bfx8 bk = *(const bfx8*)&Kl[sj * 16 + lrow][kb];
            sacc[sj] = __builtin_amdgcn_mfma_f32_16x16x32_bf16(aq[kk], bk, sacc[sj], 0, 0, 0);
        }
    }

    const float scale = 0.03608439182435161f;   // 1/sqrt(768)
    float inv[4];
#pragma unroll
    for (int j = 0; j < 4; ++j) {
        const int t = t0 + lhi * 4 + j;
        float m = -1e30f;
#pragma unroll
        for (int sj = 0; sj < 8; ++sj) {
            int s = sj * 16 + lrow;
            float vv = sacc[sj][j] * scale;
            vv = (s <= t) ? vv : -1e30f;
            sacc[sj][j] = vv;
            m = fmaxf(m, vv);
        }
#pragma unroll
        for (int d = 1; d < 16; d <<= 1) m = fmaxf(m, __shfl_xor(m, d));
        float sum = 0.f;
#pragma unroll
        for (int sj = 0; sj < 8; ++sj) {
            float e = __expf(sacc[sj][j] - m);
            sacc[sj][j] = e;
            sum += e;
        }
#pragma unroll
        for (int d = 1; d < 16; d <<= 1) sum += __shfl_xor(sum, d);
        inv[j] = 1.0f / sum;
    }

    __syncthreads();

    unsigned short* Pl = &Kl[0][0] + (size_t)w * (16 * 136);
#pragma unroll
    for (int sj = 0; sj < 8; ++sj)
#pragma unroll
        for (int j = 0; j < 4; ++j)
            Pl[(lhi * 4 + j) * 136 + sj * 16 + lrow] = f2bf(sacc[sj][j] * inv[j]);

    bfx8 pa[4];
#pragma unroll
    for (int kk = 0; kk < 4; ++kk)
        pa[kk] = *(const bfx8*)(Pl + lrow * 136 + kk * 32 + lhi * 8);

    f32x4 oacc[16];
#pragma unroll
    for (int ni = 0; ni < 16; ++ni) oacc[ni] = zero;
#pragma unroll
    for (int ni = 0; ni < 16; ++ni) {
#pragma unroll
        for (int kk = 0; kk < 4; ++kk) {
            bfx8 bv = *(const bfx8*)&Vt[ni * 16 + lrow][kk * 32 + lhi * 8];
            oacc[ni] = __builtin_amdgcn_mfma_f32_16x16x32_bf16(pa[kk], bv, oacc[ni], 0, 0, 0);
        }
    }

    float* Ob = Out + (size_t)b * 128 * 256;
#pragma unroll
    for (int ni = 0; ni < 16; ++ni) {
#pragma unroll
        for (int j = 0; j < 4; ++j) {
            const int t = t0 + lhi * 4 + j;
            const int h = ni * 16 + lrow;
            Ob[(size_t)t * 256 + h] = oacc[ni][j];
        }
    }
}

// ---------------------------------------------------------------------------
extern "C" void kernel_launch(void* const* d_in, const int* in_sizes, int n_in,
                              void* d_out, int out_size, void* d_ws, size_t ws_size,
                              hipStream_t stream) {
    (void)in_sizes; (void)n_in; (void)out_size;
    const float* X  = (const float*)d_in[0];   // res_stream [512,128,768]
    const float* Wk = (const float*)d_in[1];   // [768,256]
    const float* Wq = (const float*)d_in[2];
    const float* Wv = (const float*)d_in[3];

    const size_t WT_E  = (size_t)768 * 768;
    const size_t QKV_E = (size_t)512 * 3 * 32768;
    unsigned short* WT  = (unsigned short*)d_ws;
    unsigned short* QKV = WT + WT_E;
    unsigned short* Xb  = QKV + QKV_E;
    float* Out = (float*)d_out;

    const long perBatch = 128 * 768;                 // elements per batch
    size_t used = (WT_E + QKV_E) * 2;                // bytes
    size_t availB = (ws_size > used) ? ws_size - used : 0;
    int chunk = (int)((availB / 2) / (size_t)perBatch);   // batches that fit
    if (chunk > 512) chunk = 512;
    if (chunk < 1) chunk = 1;

    prep_w<<<768, 768, 0, stream>>>(Wk, Wq, Wv, WT);
    for (int b0 = 0; b0 < 512; b0 += chunk) {
        const int cb = (512 - b0 < chunk) ? (512 - b0) : chunk;
        const long n = (long)cb * perBatch;
        cvt_x<<<2048, 256, 0, stream>>>(X + (size_t)b0 * perBatch, Xb, n);
        const int nwg = cb * 3;
        qkv_gemm<<<nwg, 256, 0, stream>>>(Xb, WT, QKV, b0, nwg);
    }
    attn<<<512, 512, 0, stream>>>(QKV, Out);
}